// Round 10
// baseline (613.835 us; speedup 1.0000x reference)
//
#include <hip/hip_runtime.h>
#include <math.h>

typedef __attribute__((ext_vector_type(8))) short short8;
typedef __attribute__((ext_vector_type(4))) float f32x4;
typedef unsigned short u16;

__device__ __forceinline__ float b2f(u16 u) {
    union { unsigned u; float f; } c; c.u = ((unsigned)u) << 16; return c.f;
}
__device__ __forceinline__ u16 f2b(float f) {
    unsigned u = __float_as_uint(f);
    u += 0x7fffu + ((u >> 16) & 1u);   // RNE
    return (u16)(u >> 16);
}

// fp32 -> bf16 (RNE), n multiple of 8, one thread per 8 elements
__global__ __launch_bounds__(256) void cvt_f32_bf16(const float* __restrict__ src,
                                                    u16* __restrict__ dst, int n) {
    const int i = (blockIdx.x * 256 + threadIdx.x) * 8;
    if (i >= n) return;
    const float4 a = *(const float4*)&src[i];
    const float4 b = *(const float4*)&src[i + 4];
    short8 o;
    o[0] = (short)f2b(a.x); o[1] = (short)f2b(a.y);
    o[2] = (short)f2b(a.z); o[3] = (short)f2b(a.w);
    o[4] = (short)f2b(b.x); o[5] = (short)f2b(b.y);
    o[6] = (short)f2b(b.z); o[7] = (short)f2b(b.w);
    *(short8*)&dst[i] = o;
}

// 4 weight matrices (1M fp32 each) -> contiguous bf16; z selects source
__global__ __launch_bounds__(256) void cvt_weights(
    const float* __restrict__ w0, const float* __restrict__ w1,
    const float* __restrict__ w2, const float* __restrict__ w3,
    u16* __restrict__ dst) {
    const int z = blockIdx.z;
    const float* src = (z == 0) ? w0 : (z == 1) ? w1 : (z == 2) ? w2 : w3;
    const int i = (blockIdx.x * 256 + threadIdx.x) * 8;
    const float4 a = *(const float4*)&src[i];
    const float4 b = *(const float4*)&src[i + 4];
    short8 o;
    o[0] = (short)f2b(a.x); o[1] = (short)f2b(a.y);
    o[2] = (short)f2b(a.z); o[3] = (short)f2b(a.w);
    o[4] = (short)f2b(b.x); o[5] = (short)f2b(b.y);
    o[6] = (short)f2b(b.z); o[7] = (short)f2b(b.w);
    *(short8*)&dst[(long)z * 1024 * 1024 + i] = o;
}

// 128x128-tile GEMM, C = scale * A[tm*128.., K] @ W[tn*128.., K]^T.
// R10: FRAGMENT-DIRECT, BARRIER-FREE K-loop. No LDS: each wave loads its
// MFMA A/B fragments straight from global (saddr + loop-invariant per-lane
// voffset) into a 2-slot register pipeline. With no __syncthreads there is
// no forced vmcnt(0) drain -- the compiler keeps the next step's 8 loads in
// flight across the current step's MFMAs (partial vmcnt waits), the AITER
// pattern. MFMA order identical to the LDS version (bit-identical output).
template<typename OT>
__device__ __forceinline__ void gemm_body(
    const u16* __restrict__ A, const u16* __restrict__ W, OT* __restrict__ C,
    int lda, int ldw, int ldc, int K, float scale, int tm, int tn)
{
    const int m0 = tm * 128;
    const int n0 = tn * 128;
    const int t = threadIdx.x;
    const int lane = t & 63;
    const int wave = t >> 6;
    const int wm = (wave & 1) * 64;
    const int wn = (wave >> 1) * 64;
    const int fr = lane & 15;   // fragment row (m / n)
    const int fq = lane >> 4;   // k-quad: elements fq*8..fq*8+7

    // per-lane loop-INVARIANT element offsets; uniform bases advance by 32
    int offA[4], offB[4];
#pragma unroll
    for (int i = 0; i < 4; ++i) offA[i] = (m0 + wm + i * 16 + fr) * lda + fq * 8;
#pragma unroll
    for (int j = 0; j < 4; ++j) offB[j] = (n0 + wn + j * 16 + fr) * ldw + fq * 8;
    const u16* Au = A;
    const u16* Wu = W;

    f32x4 acc[4][4];
#pragma unroll
    for (int i = 0; i < 4; ++i)
#pragma unroll
        for (int j = 0; j < 4; ++j)
            acc[i][j] = (f32x4){0.f, 0.f, 0.f, 0.f};

    short8 af[2][4], bf[2][4];

    // prologue: fragments for step 0 -> slot 0
#pragma unroll
    for (int i = 0; i < 4; ++i) af[0][i] = *(const short8*)(Au + offA[i]);
#pragma unroll
    for (int j = 0; j < 4; ++j) bf[0][j] = *(const short8*)(Wu + offB[j]);
    Au += 32; Wu += 32;

    const int nsteps = K >> 5;   // even for all shapes here (K = 1024 or 2048)
    for (int s = 0; s < nsteps; s += 2) {
        // issue step s+1 loads into slot 1 (always exists: nsteps even)
#pragma unroll
        for (int i = 0; i < 4; ++i) af[1][i] = *(const short8*)(Au + offA[i]);
#pragma unroll
        for (int j = 0; j < 4; ++j) bf[1][j] = *(const short8*)(Wu + offB[j]);
        Au += 32; Wu += 32;

        // compute step s from slot 0 (waits only slot-0 loads)
#pragma unroll
        for (int i = 0; i < 4; ++i)
#pragma unroll
            for (int j = 0; j < 4; ++j)
                acc[i][j] = __builtin_amdgcn_mfma_f32_16x16x32_bf16(af[0][i], bf[0][j], acc[i][j], 0, 0, 0);

        // issue step s+2 loads into slot 0
        if (s + 2 < nsteps) {
#pragma unroll
            for (int i = 0; i < 4; ++i) af[0][i] = *(const short8*)(Au + offA[i]);
#pragma unroll
            for (int j = 0; j < 4; ++j) bf[0][j] = *(const short8*)(Wu + offB[j]);
            Au += 32; Wu += 32;
        }

        // compute step s+1 from slot 1
#pragma unroll
        for (int i = 0; i < 4; ++i)
#pragma unroll
            for (int j = 0; j < 4; ++j)
                acc[i][j] = __builtin_amdgcn_mfma_f32_16x16x32_bf16(af[1][i], bf[1][j], acc[i][j], 0, 0, 0);
    }

    // C/D layout: col = lane&15, row = quad*4 + reg  [verified m89/m91]
#pragma unroll
    for (int i = 0; i < 4; ++i) {
#pragma unroll
        for (int j = 0; j < 4; ++j) {
            const int row0 = m0 + wm + i * 16 + fq * 4;
            const int col = n0 + wn + j * 16 + fr;
#pragma unroll
            for (int r = 0; r < 4; ++r) {
                const int row = row0 + r;
                const float val = acc[i][j][r] * scale;
                if (sizeof(OT) == 2) {
                    ((u16*)C)[(long)row * ldc + col] = f2b(val);
                } else {
                    ((float*)C)[(long)row * ldc + col] = val;
                }
            }
        }
    }
}

// QKV fused, XCD-aware: 1536 blocks; XCD k owns m-strips [8k,8k+8) x all n x all z.
__global__ __launch_bounds__(256) void gemm_qkv(
    const u16* __restrict__ A, const u16* __restrict__ W, u16* __restrict__ C)
{
    const int id = blockIdx.x;
    const int xcd = id & 7;
    const int s = id >> 3;          // [0,192)
    const int tn = s & 7;
    const int ml = (s >> 3) & 7;
    const int z = s >> 6;           // [0,3)
    const int tm = xcd * 8 + ml;
    gemm_body<u16>(A, W + (long)z * (1024 * 1024), C + (long)z * (8 * 1024 * 1024),
                   1024, 1024, 1024, 1024, 1.0f, tm, tn);
}

// scores + UT fused, XCD-aware: 2048 blocks.
// scores (s<128): XCD = 2b + m-half -> per-XCD: q-half 2MB + k 4MB.
// UT (128<=s<192): XCD = 2b + m-quarter-pair -> wo 1MB + v[b] 4MB.
__global__ __launch_bounds__(256) void gemm_dual(
    const u16* __restrict__ q, const u16* __restrict__ kk, u16* __restrict__ sc,
    const u16* __restrict__ wo, const u16* __restrict__ v, u16* __restrict__ UT)
{
    const long M1 = 1024 * 1024;
    const int id = blockIdx.x;
    const int xcd = id & 7;
    const int s = id >> 3;          // [0,256)
    const int b = xcd >> 1;
    if (s < 128) {
        const int tn = s & 15;
        const int tm = (xcd & 1) * 8 + (s >> 4);   // [0,16)
        gemm_body<u16>(q + b * 2 * M1, kk + b * 2 * M1, sc + b * 4 * M1,
                       1024, 1024, 2048, 1024, 0.03125f, tm, tn);
    } else if (s < 192) {
        const int s2 = s - 128;                    // [0,64)
        const int tn = s2 & 15;
        const int tm = (xcd & 1) * 4 + (s2 >> 4);  // [0,8)
        gemm_body<u16>(wo, v + b * 2 * M1, UT + b * 2 * M1,
                       1024, 1024, 2048, 1024, 1.0f, tm, tn);
    }
    // s >= 192: exit (no barriers anywhere in the body now)
}

// out = P @ UT^T, XCD-aware: 512 blocks; XCD = 2b + m-half.
__global__ __launch_bounds__(256) void gemm_pv(
    const u16* __restrict__ P, const u16* __restrict__ UT, float* __restrict__ out)
{
    const long M1 = 1024 * 1024;
    const int id = blockIdx.x;
    const int xcd = id & 7;
    const int s = id >> 3;          // [0,64)
    const int b = xcd >> 1;
    const int tn = s & 7;
    const int tm = (xcd & 1) * 8 + (s >> 3);       // [0,16)
    gemm_body<float>(P + b * 4 * M1, UT + b * 2 * M1, out + b * 2 * M1,
                     2048, 2048, 1024, 2048, 1.0f, tm, tn);
}

// interleaved RoPE in-place on q and k: rows = b*2048+s, 512 pairs per row
__global__ __launch_bounds__(256) void rope_kernel(u16* q, u16* k) {
    const int row = blockIdx.x;
    const int pos = row & 2047;
    u16* p = (blockIdx.y ? k : q) + (long)row * 1024;
#pragma unroll
    for (int it = 0; it < 2; ++it) {
        const int i = threadIdx.x + it * 256;
        const float e = (float)i * (1.0f / 512.0f);
        const float inv = powf(10000.0f, -e);
        const float ang = (float)pos * inv;
        float s, c;
        sincosf(ang, &s, &c);
        const float xr = b2f(p[2 * i]);
        const float xi = b2f(p[2 * i + 1]);
        p[2 * i]     = f2b(xr * c - xi * s);
        p[2 * i + 1] = f2b(xr * s + xi * c);
    }
}

// row-wise softmax over 2048 bf16 entries, in-place safe; one block per row
__global__ __launch_bounds__(256) void softmax_kernel(const u16* __restrict__ S, u16* __restrict__ P) {
    const long row = blockIdx.x;
    const u16* src = S + row * 2048;
    u16* dst = P + row * 2048;
    const int t = threadIdx.x;
    const int lane = t & 63;
    const int wave = t >> 6;
    __shared__ float red[4];

    float v[8];
    const short8 raw = *(const short8*)&src[t * 8];
#pragma unroll
    for (int i = 0; i < 8; ++i) v[i] = b2f((u16)raw[i]);

    float m = v[0];
#pragma unroll
    for (int i = 1; i < 8; ++i) m = fmaxf(m, v[i]);
    for (int o = 32; o > 0; o >>= 1) m = fmaxf(m, __shfl_xor(m, o, 64));
    if (lane == 0) red[wave] = m;
    __syncthreads();
    m = fmaxf(fmaxf(red[0], red[1]), fmaxf(red[2], red[3]));
    __syncthreads();

    float sum = 0.f;
#pragma unroll
    for (int i = 0; i < 8; ++i) { v[i] = expf(v[i] - m); sum += v[i]; }
    for (int o = 32; o > 0; o >>= 1) sum += __shfl_xor(sum, o, 64);
    if (lane == 0) red[wave] = sum;
    __syncthreads();
    sum = red[0] + red[1] + red[2] + red[3];
    const float is = 1.0f / sum;

    short8 outv;
#pragma unroll
    for (int i = 0; i < 8; ++i) outv[i] = (short)f2b(v[i] * is);
    *(short8*)&dst[t * 8] = outv;
}

extern "C" void kernel_launch(void* const* d_in, const int* in_sizes, int n_in,
                              void* d_out, int out_size, void* d_ws, size_t ws_size,
                              hipStream_t stream)
{
    (void)in_sizes; (void)n_in; (void)out_size; (void)ws_size;
    const float* x  = (const float*)d_in[0];
    const float* wq = (const float*)d_in[1];
    const float* wk = (const float*)d_in[2];
    const float* wv = (const float*)d_in[3];
    const float* wo = (const float*)d_in[4];
    float* out = (float*)d_out;

    // workspace layout (bf16 elements), 104 MB total
    const long M1 = 1024 * 1024;
    u16* ws  = (u16*)d_ws;
    u16* xb  = ws;               // [8192][1024] bf16 x; reused as UT after QKV
    u16* wqb = xb + 8 * M1;      // [4][1024][1024] wq,wk,wv,wo contiguous
    u16* wob = wqb + 3 * M1;
    u16* q   = wqb + 4 * M1;     // [8192][1024]; kk, v contiguous after
    u16* kk  = q + 8 * M1;
    u16* v   = kk + 8 * M1;
    u16* sc  = v + 8 * M1;       // [4][2048][2048], softmax in-place
    u16* UT  = xb;               // alias: [4][1024][2048], xb dead after QKV

    const dim3 blk(256);

    // fp32 -> bf16 conversions (2 dispatches)
    cvt_f32_bf16<<<dim3(4096), blk, 0, stream>>>(x, xb, 8 * 1024 * 1024);
    cvt_weights<<<dim3(512, 1, 4), blk, 0, stream>>>(wq, wk, wv, wo, wqb);

    // QKV fused (M=8192, N=1024, K=1024 per z), XCD-aware 1-D grid
    gemm_qkv<<<dim3(1536), blk, 0, stream>>>(xb, wqb, q);

    rope_kernel<<<dim3(8192, 2), blk, 0, stream>>>(q, kk);

    // scores (q@k^T/32) + UT (wo@v^T) fused, XCD-aware
    gemm_dual<<<dim3(2048), blk, 0, stream>>>(q, kk, sc, wob, v, UT);

    softmax_kernel<<<dim3(8192), blk, 0, stream>>>(sc, sc);

    // out[b] = P[b] @ UT[b]^T  (M=2048, N=1024, K=2048), fp32 out, XCD-aware
    gemm_pv<<<dim3(512), blk, 0, stream>>>(sc, UT, out);
}